// Round 10
// baseline (200.390 us; speedup 1.0000x reference)
//
#include <hip/hip_runtime.h>

// LinearCRF: mean_b( logZ_b - gold_b ), B=8192, L=1024, S=3.
// Scaled linear-domain forward: lane owns a 16-step chunk, builds the 3x3
// transfer-matrix product in linear space with exact power-of-2 renorm;
// 6-stage ordered shfl_xor butterfly composes 64 chunks per wave
// (1 wave = 1 sequence per iteration). Gold score fused.
// R13: PERSISTENT GRID. R11/R12: the wall is the load path's aggregate
// service (2.8 TB/s), invariant to per-wave MLP (asm-forced 20-deep burst
// = no change) and to coalescing (R4). crf_loads occupancy 46% = one-shot
// drain signature: all 8192 waves burst at t=0, completions spread
// uniformly, machine half-empty on average. R5 (3.5 TB/s) and m13
// (6.3 TB/s) both issue CONTINUOUSLY. Fix: 512 blocks x 4 waves, each
// wave processes 4 sequences (seq = it*2048 + gwid: chip sweeps
// contiguous 42MB windows, L3-friendly). Load stalls overlap other
// waves' compute for the whole kernel life; drain tail ~12% not ~50%.
// T2/tk hoisted; per-wave partials accumulate in-register; one store
// per block (ws = 512 floats). No barriers inside the seq loop.

#define LOG2E 1.4426950408889634f
#define LN2   0.6931471805599453f

constexpr int B = 8192;
constexpr int L = 1024;
constexpr int SEQS_PER_BLOCK = 4;     // 4 waves of 64 per block
constexpr int NBLK = 512;             // persistent: 2048 waves, 4 seqs each
constexpr int ITERS = B / (NBLK * SEQS_PER_BLOCK);  // 4

__device__ __forceinline__ float fexp2(float x) { return __builtin_amdgcn_exp2f(x); }
__device__ __forceinline__ float flog2(float x) { return __builtin_amdgcn_logf(x); }

__device__ __forceinline__ float f4get(const float4& v, int c) {
  return c == 0 ? v.x : (c == 1 ? v.y : (c == 2 ? v.z : v.w));
}
__device__ __forceinline__ int i4get(const int4& v, int c) {
  return c == 0 ? v.x : (c == 1 ? v.y : (c == 2 ? v.z : v.w));
}

__device__ __forceinline__ float mux3(float x0, float x1, float x2, int i) {
  return (i == 0) ? x0 : ((i == 1) ? x1 : x2);
}
// transitions[p][c] via cndmask chain (no dynamic register indexing)
__device__ __forceinline__ float trmux(const float* __restrict__ T2, int p, int c) {
  const float r0 = mux3(T2[0], T2[1], T2[2], c);
  const float r1 = mux3(T2[3], T2[4], T2[5], c);
  const float r2 = mux3(T2[6], T2[7], T2[8], c);
  return mux3(r0, r1, r2, p);
}

__device__ __forceinline__ void matmul3(float* __restrict__ D,
                                        const float* __restrict__ A,
                                        const float* __restrict__ Bm) {
  #pragma unroll
  for (int i = 0; i < 3; ++i)
    #pragma unroll
    for (int j = 0; j < 3; ++j)
      D[i * 3 + j] = A[i * 3 + 0] * Bm[0 * 3 + j] +
                     A[i * 3 + 1] * Bm[1 * 3 + j] +
                     A[i * 3 + 2] * Bm[2 * 3 + j];
}

// Exact power-of-2 renormalization: P *= 2^-ex, scale += ex.
__device__ __forceinline__ void renorm3(float* __restrict__ P, float& scale) {
  float m = P[0];
  #pragma unroll
  for (int e = 1; e < 9; ++e) m = fmaxf(m, P[e]);
  int ex;
  (void)frexpf(m, &ex);
  #pragma unroll
  for (int e = 0; e < 9; ++e) P[e] = ldexpf(P[e], -ex);
  scale += (float)ex;
}

__global__ __launch_bounds__(256, 4) void crf_main(
    const float* __restrict__ em, const float* __restrict__ mask,
    const float* __restrict__ trans, const int* __restrict__ tags,
    float* __restrict__ ws) {
  const int lane = threadIdx.x & 63;
  const int wid = threadIdx.x >> 6;
  const int gwid = blockIdx.x * SEQS_PER_BLOCK + wid;   // [0, 2048)

  // Transitions: log2 domain + linear form (uniform, loop-invariant).
  float T2[9], tk[9];
  #pragma unroll
  for (int e = 0; e < 9; ++e) {
    T2[e] = trans[e] * LOG2E;
    tk[e] = fexp2(T2[e]);
  }

  float wsum = 0.f;   // lane 0 accumulates (logZ - gold) over ITERS seqs

  #pragma unroll 1
  for (int it = 0; it < ITERS; ++it) {
    const int b = it * (NBLK * SEQS_PER_BLOCK) + gwid;  // window sweep

    const float4* em4 = (const float4*)(em + (size_t)b * (L * 3)) + lane * 12;
    const float4* mk4 = (const float4*)(mask + (size_t)b * L) + lane * 4;
    const int4*   tg4 = (const int4*)(tags + (size_t)b * L) + lane * 4;

    float4 E[12];
    #pragma unroll
    for (int u = 0; u < 12; ++u) E[u] = em4[u];
    float4 MK[4];
    #pragma unroll
    for (int u = 0; u < 4; ++u) MK[u] = mk4[u];
    int4 TG[4];
    #pragma unroll
    for (int u = 0; u < 4; ++u) TG[u] = tg4[u];

    float P[9] = {1.f, 0.f, 0.f, 0.f, 1.f, 0.f, 0.f, 0.f, 1.f};
    float scale = 0.f, gold = 0.f;
    float a0 = 0.f, a1 = 0.f, a2 = 0.f;   // step-0 linear emissions (lane 0)
    float e0_sel = 0.f, mk0 = 0.f;        // deferred step-0 gold term
    int tag0 = 0, prev = 0;

    #pragma unroll
    for (int s = 0; s < 16; ++s) {
      const float ev0 = f4get(E[(3 * s + 0) >> 2], (3 * s + 0) & 3) * LOG2E;
      const float ev1 = f4get(E[(3 * s + 1) >> 2], (3 * s + 1) & 3) * LOG2E;
      const float ev2 = f4get(E[(3 * s + 2) >> 2], (3 * s + 2) & 3) * LOG2E;
      const float m   = f4get(MK[s >> 2], s & 3);
      const int   cur = i4get(TG[s >> 2], s & 3);

      // ---- gold score (log2 domain) ----
      const float e = mux3(ev0, ev1, ev2, cur);
      if (s == 0) {
        e0_sel = e; mk0 = m; tag0 = cur;  // cross-lane prev tag fixed up later
      } else {
        gold = fmaf(trmux(T2, prev, cur) + e, m, gold);
      }
      prev = cur;

      // ---- matrix step (linear domain): M = act ? tk.*w : I ----
      const float w0 = fexp2(ev0);
      const float w1 = fexp2(ev1);
      const float w2 = fexp2(ev2);
      if (s == 0) { a0 = w0; a1 = w1; a2 = w2; }
      const bool act = (m > 0.f) && !(s == 0 && lane == 0);  // t=0 is alpha0
      const float g  = act ? 1.f : 0.f;
      const float c1 = 1.f - g;
      const float u0 = w0 * g, u1 = w1 * g, u2 = w2 * g;
      float M[9];
      M[0] = fmaf(tk[0], u0, c1); M[1] = tk[1] * u1;           M[2] = tk[2] * u2;
      M[3] = tk[3] * u0;          M[4] = fmaf(tk[4], u1, c1);  M[5] = tk[5] * u2;
      M[6] = tk[6] * u0;          M[7] = tk[7] * u1;           M[8] = fmaf(tk[8], u2, c1);
      float N[9];
      matmul3(N, P, M);
      #pragma unroll
      for (int e2 = 0; e2 < 9; ++e2) P[e2] = N[e2];

      if (s == 7 || s == 15) renorm3(P, scale);  // bound fp32 range
    }

    // ---- deferred step-0 gold term (needs previous lane's last tag) ----
    const int prevLast = __shfl_up(prev, 1);
    if (lane == 0) gold = fmaf(e0_sel, mk0, gold);
    else           gold = fmaf(trmux(T2, prevLast, tag0) + e0_sel, mk0, gold);
    #pragma unroll
    for (int d = 1; d < 64; d <<= 1) gold += __shfl_xor(gold, d, 64);

    // ---- ordered butterfly combine (entries <= 3^6=729: no renorm) ----
    #pragma unroll
    for (int d = 1; d < 64; d <<= 1) {
      float o[9];
      #pragma unroll
      for (int e = 0; e < 9; ++e) o[e] = __shfl_xor(P[e], d, 64);
      const float osc = __shfl_xor(scale, d, 64);
      const bool later = (lane & d) != 0;  // self covers the later segment
      float A[9], Bm[9];
      #pragma unroll
      for (int e = 0; e < 9; ++e) {
        A[e]  = later ? o[e] : P[e];
        Bm[e] = later ? P[e] : o[e];
      }
      float N[9];
      matmul3(N, A, Bm);
      #pragma unroll
      for (int e = 0; e < 9; ++e) P[e] = N[e];
      scale += osc;
    }

    // ---- per-seq finalize: accumulate on lane 0 ----
    if (lane == 0) {
      const float z = a0 * (P[0] + P[1] + P[2]) +
                      a1 * (P[3] + P[4] + P[5]) +
                      a2 * (P[6] + P[7] + P[8]);
      wsum += LN2 * (scale + flog2(z) - gold);
    }
  }

  // ---- block partial -> workspace (one store per block, no atomic) ----
  __shared__ float red[SEQS_PER_BLOCK];
  if (lane == 0) red[wid] = wsum;
  __syncthreads();
  if (threadIdx.x == 0) {
    ws[blockIdx.x] = red[0] + red[1] + red[2] + red[3];
  }
}

// Reduce 512 block partials -> mean. One block, no atomics.
__global__ __launch_bounds__(256) void crf_reduce(
    const float* __restrict__ ws, float* __restrict__ out) {
  const int t = threadIdx.x;
  const float4* w4 = (const float4*)ws;   // 512 floats = 128 float4
  float s = 0.f;
  if (t < 128) {
    const float4 v = w4[t];
    s = (v.x + v.y) + (v.z + v.w);
  }
  #pragma unroll
  for (int d = 1; d < 64; d <<= 1) s += __shfl_xor(s, d, 64);
  __shared__ float red[4];
  if ((t & 63) == 0) red[t >> 6] = s;
  __syncthreads();
  if (t == 0) out[0] = (red[0] + red[1] + red[2] + red[3]) * (1.0f / (float)B);
}

extern "C" void kernel_launch(void* const* d_in, const int* in_sizes, int n_in,
                              void* d_out, int out_size, void* d_ws, size_t ws_size,
                              hipStream_t stream) {
  const float* em    = (const float*)d_in[0];
  const float* mask  = (const float*)d_in[1];
  const float* trans = (const float*)d_in[2];
  const int*   tags  = (const int*)d_in[3];
  float* out = (float*)d_out;
  float* ws  = (float*)d_ws;

  crf_main<<<NBLK, 256, 0, stream>>>(em, mask, trans, tags, ws);
  crf_reduce<<<1, 256, 0, stream>>>(ws, out);
}